// Round 1
// 354.394 us; speedup vs baseline: 1.0869x; 1.0869x over previous
//
#include <hip/hip_runtime.h>

#define HIDDEN 128
#define NPB 128          // nodes per bucket (b = src >> 7)
#define CHUNK 4096       // edges per bin_k block
#define SCAP 3072        // sort_k LDS edge capacity (bucket mean 2048, sigma 45)

typedef __attribute__((ext_vector_type(8))) short bf16x8;
typedef __attribute__((ext_vector_type(4))) float f32x4;

static __device__ __forceinline__ ushort f2bf(float f) {
    uint u = __float_as_uint(f);
    uint r = (u + 0x7fffu + ((u >> 16) & 1u)) >> 16;   // round-to-nearest-even
    return (ushort)r;
}

// split fp32 into bf16 head + bf16 residual (head + lo covers ~17 mantissa bits)
static __device__ __forceinline__ void split1(float f, ushort& h, ushort& l) {
    ushort hh = f2bf(f);
    float hf = __uint_as_float(((uint)hh) << 16);
    h = hh;
    l = f2bf(f - hf);          // exact residual, then RNE to bf16
}

static __device__ __forceinline__ bf16x8 mkfrag(ushort4 a, ushort4 b) {
    bf16x8 f;
    f[0] = (short)a.x; f[1] = (short)a.y; f[2] = (short)a.z; f[3] = (short)a.w;
    f[4] = (short)b.x; f[5] = (short)b.y; f[6] = (short)b.z; f[7] = (short)b.w;
    return f;
}

// ---------------------------------------------------------------------------
// Per-node degree count (int atomics, cheap)
// ---------------------------------------------------------------------------
__global__ __launch_bounds__(256) void count_k(
    const int* __restrict__ ei, int* __restrict__ cnt, int E)
{
    int e = blockIdx.x * blockDim.x + threadIdx.x;
    if (e < E) atomicAdd(&cnt[ei[e]], 1);
}

// ---------------------------------------------------------------------------
// Hierarchical exclusive scan of cnt -> offs (3 phases). scan3 also emits
// bucket write cursors gcur[b] = offs[b*NPB].
// ---------------------------------------------------------------------------
__global__ __launch_bounds__(1024) void scan1_k(
    const int* __restrict__ cnt, int* __restrict__ offs, int* __restrict__ bsum,
    int N)
{
    __shared__ int s[1024];
    const int t = threadIdx.x;
    const int g = blockIdx.x * 1024 + t;
    int x = (g < N) ? cnt[g] : 0;
    s[t] = x;
    __syncthreads();
    #pragma unroll
    for (int off = 1; off < 1024; off <<= 1) {
        int v = (t >= off) ? s[t - off] : 0;
        __syncthreads();
        s[t] += v;
        __syncthreads();
    }
    if (g < N) offs[g] = s[t] - x;
    if (t == 1023) bsum[blockIdx.x] = s[1023];
}

__global__ __launch_bounds__(1024) void scan2_k(
    const int* __restrict__ bsum, int* __restrict__ boff,
    int* __restrict__ offs, int B, int N, int E)
{
    __shared__ int s[1024];
    const int t = threadIdx.x;
    int x = (t < B) ? bsum[t] : 0;
    s[t] = x;
    __syncthreads();
    #pragma unroll
    for (int off = 1; off < 1024; off <<= 1) {
        int v = (t >= off) ? s[t - off] : 0;
        __syncthreads();
        s[t] += v;
        __syncthreads();
    }
    if (t < B) boff[t] = s[t] - x;
    if (t == 0) offs[N] = E;
}

__global__ __launch_bounds__(1024) void scan3_k(
    int* __restrict__ offs, int* __restrict__ gcur,
    const int* __restrict__ boff, int N)
{
    int g = blockIdx.x * 1024 + threadIdx.x;
    if (g < N) {
        int v = offs[g] + boff[blockIdx.x];
        offs[g] = v;
        if ((g & (NPB - 1)) == 0) gcur[g >> 7] = v;   // bucket base cursor
    }
}

// ---------------------------------------------------------------------------
// Bucket partition (line-dense scatter). Block = 4096-edge chunk: LDS hist ->
// one global reservation per (block,bucket) -> rank -> scatter {tgt, lo|p15}.
// ---------------------------------------------------------------------------
__global__ __launch_bounds__(256) void bin_k(
    const int* __restrict__ ei, const float* __restrict__ prob,
    int* __restrict__ gcur, int2* __restrict__ ed, int E, int NB)
{
    __shared__ int hist[1024];
    __shared__ int base[1024];
    const int t  = threadIdx.x;
    const int e0 = blockIdx.x * CHUNK;

    for (int i = t; i < NB; i += 256) hist[i] = 0;
    __syncthreads();

    int  bs[16];
    int2 pl[16];
    #pragma unroll
    for (int j = 0; j < 16; ++j) {
        int e = e0 + j * 256 + t;
        if (e < E) {
            int src = ei[e];
            int tgt = ei[E + e];
            int p15 = min((int)(prob[e] * 32768.0f + 0.5f), 32767);
            int b   = src >> 7;
            bs[j] = b;
            pl[j] = make_int2(tgt, ((src & (NPB - 1)) << 15) | p15);
            atomicAdd(&hist[b], 1);
        } else bs[j] = -1;
    }
    __syncthreads();

    for (int i = t; i < NB; i += 256) {
        int c = hist[i];
        base[i] = c ? atomicAdd(&gcur[i], c) : 0;
        hist[i] = 0;
    }
    __syncthreads();

    #pragma unroll
    for (int j = 0; j < 16; ++j) {
        if (bs[j] >= 0) {
            int r = atomicAdd(&hist[bs[j]], 1);
            ed[base[bs[j]] + r] = pl[j];
        }
    }
}

// ---------------------------------------------------------------------------
// In-bucket node sort (in place). Block = bucket: stage edges in LDS,
// rank by local node via LDS hist, write back node-sorted (CSR order).
// ---------------------------------------------------------------------------
__global__ __launch_bounds__(256) void sort_k(
    const int* __restrict__ offs, int2* __restrict__ ed, int N)
{
    __shared__ int2 buf[SCAP];
    __shared__ int  loc[NPB];
    __shared__ int  h[NPB];
    const int b = blockIdx.x;
    const int t = threadIdx.x;
    const int nb0 = b * NPB;
    const int nn  = min(NPB, N - nb0);

    if (t < NPB) h[t] = 0;
    if (t < nn)  loc[t] = offs[nb0 + t];
    __syncthreads();

    const int beg = loc[0];
    const int end = offs[min(nb0 + NPB, N)];
    const int c   = end - beg;

    for (int i = t; i < c && i < SCAP; i += 256) buf[i] = ed[beg + i];
    __syncthreads();
    for (int i = t; i < c && i < SCAP; i += 256) {
        int2 e = buf[i];
        int lo = (e.y >> 15) & (NPB - 1);
        int r  = atomicAdd(&h[lo], 1);
        ed[loc[lo] + r] = e;
    }
}

// ---------------------------------------------------------------------------
// One-shot: split W (128x128 fp32) into bf16 head/residual planes.
// ---------------------------------------------------------------------------
__global__ __launch_bounds__(256) void wprep_k(
    const float* __restrict__ W, ushort* __restrict__ wh, ushort* __restrict__ wl)
{
    int i = blockIdx.x * 256 + threadIdx.x;   // grid = 64 blocks, exact
    ushort h, l;
    split1(W[i], h, l);
    wh[i] = h;
    wl[i] = l;
}

// ---------------------------------------------------------------------------
// hp = bf16(hidden @ W^T) via MFMA with bf16x3 split precision:
//   A*W ~= Ah*Wh + Ah*Wl + Al*Wh   (error ~2^-17 rel, << bf16 output ulp)
// Block: 128 rows x 128 cols, 4 waves in 2x2, each wave 64x64.
// A tile staged in LDS as swizzled bf16 hi/lo (64 KB -> 2 blocks/CU).
// W frags held in registers (loaded from pre-split planes, L2-resident).
// mfma_f32_16x16x32_bf16 layouts:
//   A: row = l&15,  k = 4*(l>>4) + (i&3) + 16*(i>>2)
//   B: col = l&15,  k = same
//   D: col = l&15,  row = 4*(l>>4) + reg
// ---------------------------------------------------------------------------
__global__ __launch_bounds__(256, 2) void gemm_mfma_k(
    const float* __restrict__ A, const ushort* __restrict__ wh,
    const ushort* __restrict__ wl, ushort* __restrict__ hp, int N)
{
    __shared__ ushort a_hi[128 * 128];   // 32 KB, XOR-swizzled
    __shared__ ushort a_lo[128 * 128];   // 32 KB

    const int t  = threadIdx.x;
    const int n0 = blockIdx.x * 128;

    // ---- stage A tile: fp32 -> (hi, lo) bf16, swizzle byte ^= (row&7)<<4 ----
    #pragma unroll
    for (int i = 0; i < 16; ++i) {
        int idx4 = t + 256 * i;           // float4 index within tile (0..4095)
        int row  = idx4 >> 5;             // 32 float4 per 128-wide row
        int kq   = idx4 & 31;             // float4 col
        int n    = n0 + row;
        float4 v = (n < N) ? ((const float4*)A)[(size_t)n * 32 + kq]
                           : make_float4(0.f, 0.f, 0.f, 0.f);
        ushort4 h, l;
        split1(v.x, h.x, l.x);
        split1(v.y, h.y, l.y);
        split1(v.z, h.z, l.z);
        split1(v.w, h.w, l.w);
        uint off = (uint)((row << 8) + (kq << 3)) ^ (uint)((row & 7) << 4);
        *(ushort4*)((char*)a_hi + off) = h;
        *(ushort4*)((char*)a_lo + off) = l;
    }

    const int w  = t >> 6;
    const int l  = t & 63;
    const int wr = w >> 1;        // wave row group: rows wr*64..+63
    const int wc = w & 1;         // wave col group: cols wc*64..+63
    const int lg = l >> 4;        // k-group 0..3
    const int li = l & 15;

    // ---- W fragments in registers (issued before the barrier; latency hides) ----
    bf16x8 wfh[4][4], wfl[4][4];  // [cfrag][kstep]
    #pragma unroll
    for (int c = 0; c < 4; ++c) {
        int o = wc * 64 + c * 16 + li;
        #pragma unroll
        for (int ks = 0; ks < 4; ++ks) {
            int kb = ks * 32 + lg * 4;
            const ushort* ph = wh + o * 128 + kb;
            const ushort* pl = wl + o * 128 + kb;
            ushort4 h0 = *(const ushort4*)(ph);
            ushort4 h1 = *(const ushort4*)(ph + 16);
            ushort4 l0 = *(const ushort4*)(pl);
            ushort4 l1 = *(const ushort4*)(pl + 16);
            wfh[c][ks] = mkfrag(h0, h1);
            wfl[c][ks] = mkfrag(l0, l1);
        }
    }

    f32x4 acc[4][4];
    #pragma unroll
    for (int m = 0; m < 4; ++m)
        #pragma unroll
        for (int c = 0; c < 4; ++c)
            acc[m][c] = (f32x4){0.f, 0.f, 0.f, 0.f};

    __syncthreads();

    // ---- K loop: 4 steps of 32; 48 MFMA per step per wave ----
    #pragma unroll
    for (int ks = 0; ks < 4; ++ks) {
        int kb2 = (ks * 32 + lg * 4) * 2;          // byte offset of k-half 0
        #pragma unroll
        for (int m = 0; m < 4; ++m) {
            int row  = wr * 64 + m * 16 + li;
            uint bse = (uint)(row << 8);
            uint swz = (uint)((row & 7) << 4);
            uint o0  = (bse + kb2) ^ swz;
            uint o1  = (bse + kb2 + 32) ^ swz;     // k-half 1 (+16 elems)
            ushort4 h0 = *(ushort4*)((char*)a_hi + o0);
            ushort4 h1 = *(ushort4*)((char*)a_hi + o1);
            ushort4 q0 = *(ushort4*)((char*)a_lo + o0);
            ushort4 q1 = *(ushort4*)((char*)a_lo + o1);
            bf16x8 ah = mkfrag(h0, h1);
            bf16x8 al = mkfrag(q0, q1);
            #pragma unroll
            for (int c = 0; c < 4; ++c) {
                acc[m][c] = __builtin_amdgcn_mfma_f32_16x16x32_bf16(ah, wfh[c][ks], acc[m][c], 0, 0, 0);
                acc[m][c] = __builtin_amdgcn_mfma_f32_16x16x32_bf16(ah, wfl[c][ks], acc[m][c], 0, 0, 0);
                acc[m][c] = __builtin_amdgcn_mfma_f32_16x16x32_bf16(al, wfh[c][ks], acc[m][c], 0, 0, 0);
            }
        }
    }

    // ---- epilogue: D frag row = lg*4 + i, col = li ----
    #pragma unroll
    for (int m = 0; m < 4; ++m) {
        #pragma unroll
        for (int i = 0; i < 4; ++i) {
            int n = n0 + wr * 64 + m * 16 + lg * 4 + i;
            if (n < N) {
                ushort* dst = hp + (size_t)n * 128 + wc * 64 + li;
                #pragma unroll
                for (int c = 0; c < 4; ++c)
                    dst[c * 16] = f2bf(acc[m][c][i]);
            }
        }
    }
}

// ---------------------------------------------------------------------------
// out[n] = bias + sum_{e in CSR[n]} p_e * hp[tgt_e]
// One 64-lane wave per node; lane = bf16x2 slice; 4x unroll for MLP.
// ---------------------------------------------------------------------------
__global__ __launch_bounds__(256) void agg_k(
    const int*  __restrict__ offs,
    const int2* __restrict__ ed,
    const ushort* __restrict__ hp,
    const float* __restrict__ bias,
    float*       __restrict__ out,
    int N)
{
    int wave = (blockIdx.x * blockDim.x + threadIdx.x) >> 6;
    int l    = threadIdx.x & 63;
    if (wave >= N) return;

    float2 acc = ((const float2*)bias)[l];
    int beg = offs[wave];
    int end = offs[wave + 1];
    const uint* hpw = (const uint*)hp;   // bf16x2 per uint
    const float ps = 1.0f / 32768.0f;

    int i = beg;
    for (; i + 4 <= end; i += 4) {
        int2 d0 = ed[i], d1 = ed[i + 1], d2 = ed[i + 2], d3 = ed[i + 3];
        uint h0 = hpw[(size_t)d0.x * 64 + l];
        uint h1 = hpw[(size_t)d1.x * 64 + l];
        uint h2 = hpw[(size_t)d2.x * 64 + l];
        uint h3 = hpw[(size_t)d3.x * 64 + l];
        float p0 = (float)(d0.y & 0x7fff) * ps;
        float p1 = (float)(d1.y & 0x7fff) * ps;
        float p2 = (float)(d2.y & 0x7fff) * ps;
        float p3 = (float)(d3.y & 0x7fff) * ps;
        acc.x += p0 * __uint_as_float(h0 << 16);
        acc.y += p0 * __uint_as_float(h0 & 0xffff0000u);
        acc.x += p1 * __uint_as_float(h1 << 16);
        acc.y += p1 * __uint_as_float(h1 & 0xffff0000u);
        acc.x += p2 * __uint_as_float(h2 << 16);
        acc.y += p2 * __uint_as_float(h2 & 0xffff0000u);
        acc.x += p3 * __uint_as_float(h3 << 16);
        acc.y += p3 * __uint_as_float(h3 & 0xffff0000u);
    }
    for (; i < end; ++i) {
        int2 d = ed[i];
        uint h = hpw[(size_t)d.x * 64 + l];
        float p = (float)(d.y & 0x7fff) * ps;
        acc.x += p * __uint_as_float(h << 16);
        acc.y += p * __uint_as_float(h & 0xffff0000u);
    }

    ((float2*)(out + (size_t)wave * HIDDEN))[l] = acc;
}

extern "C" void kernel_launch(void* const* d_in, const int* in_sizes, int n_in,
                              void* d_out, int out_size, void* d_ws, size_t ws_size,
                              hipStream_t stream)
{
    const float* prob   = (const float*)d_in[0];
    const float* hidden = (const float*)d_in[1];
    const int*   ei     = (const int*)  d_in[2];
    const float* W      = (const float*)d_in[3];
    const float* bias   = (const float*)d_in[4];
    float*       out    = (float*)d_out;

    const int E  = in_sizes[0];
    const int N  = in_sizes[1] / HIDDEN;
    const int B  = (N + 1023) / 1024;        // scan blocks
    const int NB = (N + NPB - 1) / NPB;      // buckets (782)

    // Workspace layout:
    char* w = (char*)d_ws;
    int* cnt  = (int*)w;                     // N
    int* offs = cnt + N;                     // N+1
    int* bsum = offs + N + 1;                // B
    int* boff = bsum + B;                    // B
    int* gcur = boff + B;                    // NB
    size_t ib = ((size_t)(2 * N + 1 + 2 * B + NB) * 4 + 15) & ~(size_t)15;
    int2*   ed = (int2*)(w + ib);            // E * 8B
    ushort* hp = (ushort*)(w + ib + (size_t)E * 8);   // N*128 bf16
    ushort* wh = hp + (size_t)N * 128;       // 128*128 bf16 (W head)
    ushort* wl = wh + 128 * 128;             // 128*128 bf16 (W residual)

    hipMemsetAsync(cnt, 0, (size_t)N * sizeof(int), stream);

    int eb = (E + 255) / 256;
    count_k<<<eb, 256, 0, stream>>>(ei, cnt, E);
    scan1_k<<<B, 1024, 0, stream>>>(cnt, offs, bsum, N);
    scan2_k<<<1, 1024, 0, stream>>>(bsum, boff, offs, B, N, E);
    scan3_k<<<B, 1024, 0, stream>>>(offs, gcur, boff, N);
    bin_k<<<(E + CHUNK - 1) / CHUNK, 256, 0, stream>>>(ei, prob, gcur, ed, E, NB);
    sort_k<<<NB, 256, 0, stream>>>(offs, ed, N);
    wprep_k<<<64, 256, 0, stream>>>(W, wh, wl);
    gemm_mfma_k<<<(N + 127) / 128, 256, 0, stream>>>(hidden, wh, wl, hp, N);
    agg_k<<<(N + 3) / 4, 256, 0, stream>>>(offs, ed, hp, bias, out, N);
}

// Round 2
// 353.487 us; speedup vs baseline: 1.0897x; 1.0026x over previous
//
#include <hip/hip_runtime.h>

#define HIDDEN 128
#define NPB 128          // nodes per bucket (b = src >> 7)
#define CHUNK 4096       // edges per bin_k block
#define SCAP 3072        // sort_k LDS edge capacity (bucket mean 2048, sigma 45)

typedef __attribute__((ext_vector_type(8))) short bf16x8;
typedef __attribute__((ext_vector_type(4))) float f32x4;

static __device__ __forceinline__ ushort f2bf(float f) {
    uint u = __float_as_uint(f);
    uint r = (u + 0x7fffu + ((u >> 16) & 1u)) >> 16;   // round-to-nearest-even
    return (ushort)r;
}

// split fp32 into bf16 head + bf16 residual (head + lo covers ~17 mantissa bits)
static __device__ __forceinline__ void split1(float f, ushort& h, ushort& l) {
    ushort hh = f2bf(f);
    float hf = __uint_as_float(((uint)hh) << 16);
    h = hh;
    l = f2bf(f - hf);          // exact residual, then RNE to bf16
}

static __device__ __forceinline__ bf16x8 mkfrag(ushort4 a, ushort4 b) {
    bf16x8 f;
    f[0] = (short)a.x; f[1] = (short)a.y; f[2] = (short)a.z; f[3] = (short)a.w;
    f[4] = (short)b.x; f[5] = (short)b.y; f[6] = (short)b.z; f[7] = (short)b.w;
    return f;
}

// ---------------------------------------------------------------------------
// Per-node degree count (int atomics, cheap)
// ---------------------------------------------------------------------------
__global__ __launch_bounds__(256) void count_k(
    const int* __restrict__ ei, int* __restrict__ cnt, int E)
{
    int e = blockIdx.x * blockDim.x + threadIdx.x;
    if (e < E) atomicAdd(&cnt[ei[e]], 1);
}

// ---------------------------------------------------------------------------
// Hierarchical exclusive scan of cnt -> offs (3 phases). scan3 also emits
// bucket write cursors gcur[b] = offs[b*NPB].
// ---------------------------------------------------------------------------
__global__ __launch_bounds__(1024) void scan1_k(
    const int* __restrict__ cnt, int* __restrict__ offs, int* __restrict__ bsum,
    int N)
{
    __shared__ int s[1024];
    const int t = threadIdx.x;
    const int g = blockIdx.x * 1024 + t;
    int x = (g < N) ? cnt[g] : 0;
    s[t] = x;
    __syncthreads();
    #pragma unroll
    for (int off = 1; off < 1024; off <<= 1) {
        int v = (t >= off) ? s[t - off] : 0;
        __syncthreads();
        s[t] += v;
        __syncthreads();
    }
    if (g < N) offs[g] = s[t] - x;
    if (t == 1023) bsum[blockIdx.x] = s[1023];
}

__global__ __launch_bounds__(1024) void scan2_k(
    const int* __restrict__ bsum, int* __restrict__ boff,
    int* __restrict__ offs, int B, int N, int E)
{
    __shared__ int s[1024];
    const int t = threadIdx.x;
    int x = (t < B) ? bsum[t] : 0;
    s[t] = x;
    __syncthreads();
    #pragma unroll
    for (int off = 1; off < 1024; off <<= 1) {
        int v = (t >= off) ? s[t - off] : 0;
        __syncthreads();
        s[t] += v;
        __syncthreads();
    }
    if (t < B) boff[t] = s[t] - x;
    if (t == 0) offs[N] = E;
}

__global__ __launch_bounds__(1024) void scan3_k(
    int* __restrict__ offs, int* __restrict__ gcur,
    const int* __restrict__ boff, int N)
{
    int g = blockIdx.x * 1024 + threadIdx.x;
    if (g < N) {
        int v = offs[g] + boff[blockIdx.x];
        offs[g] = v;
        if ((g & (NPB - 1)) == 0) gcur[g >> 7] = v;   // bucket base cursor
    }
}

// ---------------------------------------------------------------------------
// Bucket partition (line-dense scatter). Block = 4096-edge chunk: LDS hist ->
// one global reservation per (block,bucket) -> rank -> scatter {tgt, lo|p15}.
// ---------------------------------------------------------------------------
__global__ __launch_bounds__(256) void bin_k(
    const int* __restrict__ ei, const float* __restrict__ prob,
    int* __restrict__ gcur, int2* __restrict__ ed, int E, int NB)
{
    __shared__ int hist[1024];
    __shared__ int base[1024];
    const int t  = threadIdx.x;
    const int e0 = blockIdx.x * CHUNK;

    for (int i = t; i < NB; i += 256) hist[i] = 0;
    __syncthreads();

    int  bs[16];
    int2 pl[16];
    #pragma unroll
    for (int j = 0; j < 16; ++j) {
        int e = e0 + j * 256 + t;
        if (e < E) {
            int src = ei[e];
            int tgt = ei[E + e];
            int p15 = min((int)(prob[e] * 32768.0f + 0.5f), 32767);
            int b   = src >> 7;
            bs[j] = b;
            pl[j] = make_int2(tgt, ((src & (NPB - 1)) << 15) | p15);
            atomicAdd(&hist[b], 1);
        } else bs[j] = -1;
    }
    __syncthreads();

    for (int i = t; i < NB; i += 256) {
        int c = hist[i];
        base[i] = c ? atomicAdd(&gcur[i], c) : 0;
        hist[i] = 0;
    }
    __syncthreads();

    #pragma unroll
    for (int j = 0; j < 16; ++j) {
        if (bs[j] >= 0) {
            int r = atomicAdd(&hist[bs[j]], 1);
            ed[base[bs[j]] + r] = pl[j];
        }
    }
}

// ---------------------------------------------------------------------------
// In-bucket node sort (in place). Block = bucket: stage edges in LDS,
// rank by local node via LDS hist, write back node-sorted (CSR order).
// ---------------------------------------------------------------------------
__global__ __launch_bounds__(256) void sort_k(
    const int* __restrict__ offs, int2* __restrict__ ed, int N)
{
    __shared__ int2 buf[SCAP];
    __shared__ int  loc[NPB];
    __shared__ int  h[NPB];
    const int b = blockIdx.x;
    const int t = threadIdx.x;
    const int nb0 = b * NPB;
    const int nn  = min(NPB, N - nb0);

    if (t < NPB) h[t] = 0;
    if (t < nn)  loc[t] = offs[nb0 + t];
    __syncthreads();

    const int beg = loc[0];
    const int end = offs[min(nb0 + NPB, N)];
    const int c   = end - beg;

    for (int i = t; i < c && i < SCAP; i += 256) buf[i] = ed[beg + i];
    __syncthreads();
    for (int i = t; i < c && i < SCAP; i += 256) {
        int2 e = buf[i];
        int lo = (e.y >> 15) & (NPB - 1);
        int r  = atomicAdd(&h[lo], 1);
        ed[loc[lo] + r] = e;
    }
}

// ---------------------------------------------------------------------------
// One-shot: split W (128x128 fp32) into bf16 head/residual planes.
// ---------------------------------------------------------------------------
__global__ __launch_bounds__(256) void wprep_k(
    const float* __restrict__ W, ushort* __restrict__ wh, ushort* __restrict__ wl)
{
    int i = blockIdx.x * 256 + threadIdx.x;   // grid = 64 blocks, exact
    ushort h, l;
    split1(W[i], h, l);
    wh[i] = h;
    wl[i] = l;
}

// ---------------------------------------------------------------------------
// hp = bf16(hidden @ W^T) via MFMA with bf16x3 split precision:
//   A*W ~= Ah*Wh + Ah*Wl + Al*Wh   (error ~2^-17 rel, << bf16 output ulp)
// Block: 128 rows x 128 cols, 4 waves in 2x2, each wave 64x64.
// ---------------------------------------------------------------------------
__global__ __launch_bounds__(256, 2) void gemm_mfma_k(
    const float* __restrict__ A, const ushort* __restrict__ wh,
    const ushort* __restrict__ wl, ushort* __restrict__ hp, int N)
{
    __shared__ ushort a_hi[128 * 128];   // 32 KB, XOR-swizzled
    __shared__ ushort a_lo[128 * 128];   // 32 KB

    const int t  = threadIdx.x;
    const int n0 = blockIdx.x * 128;

    // ---- stage A tile: fp32 -> (hi, lo) bf16, swizzle byte ^= (row&7)<<4 ----
    #pragma unroll
    for (int i = 0; i < 16; ++i) {
        int idx4 = t + 256 * i;           // float4 index within tile (0..4095)
        int row  = idx4 >> 5;             // 32 float4 per 128-wide row
        int kq   = idx4 & 31;             // float4 col
        int n    = n0 + row;
        float4 v = (n < N) ? ((const float4*)A)[(size_t)n * 32 + kq]
                           : make_float4(0.f, 0.f, 0.f, 0.f);
        ushort4 h, l;
        split1(v.x, h.x, l.x);
        split1(v.y, h.y, l.y);
        split1(v.z, h.z, l.z);
        split1(v.w, h.w, l.w);
        uint off = (uint)((row << 8) + (kq << 3)) ^ (uint)((row & 7) << 4);
        *(ushort4*)((char*)a_hi + off) = h;
        *(ushort4*)((char*)a_lo + off) = l;
    }

    const int w  = t >> 6;
    const int l  = t & 63;
    const int wr = w >> 1;        // wave row group: rows wr*64..+63
    const int wc = w & 1;         // wave col group: cols wc*64..+63
    const int lg = l >> 4;        // k-group 0..3
    const int li = l & 15;

    // ---- W fragments in registers (issued before the barrier; latency hides) ----
    bf16x8 wfh[4][4], wfl[4][4];  // [cfrag][kstep]
    #pragma unroll
    for (int c = 0; c < 4; ++c) {
        int o = wc * 64 + c * 16 + li;
        #pragma unroll
        for (int ks = 0; ks < 4; ++ks) {
            int kb = ks * 32 + lg * 4;
            const ushort* ph = wh + o * 128 + kb;
            const ushort* pl = wl + o * 128 + kb;
            ushort4 h0 = *(const ushort4*)(ph);
            ushort4 h1 = *(const ushort4*)(ph + 16);
            ushort4 l0 = *(const ushort4*)(pl);
            ushort4 l1 = *(const ushort4*)(pl + 16);
            wfh[c][ks] = mkfrag(h0, h1);
            wfl[c][ks] = mkfrag(l0, l1);
        }
    }

    f32x4 acc[4][4];
    #pragma unroll
    for (int m = 0; m < 4; ++m)
        #pragma unroll
        for (int c = 0; c < 4; ++c)
            acc[m][c] = (f32x4){0.f, 0.f, 0.f, 0.f};

    __syncthreads();

    // ---- K loop: 4 steps of 32; 48 MFMA per step per wave ----
    #pragma unroll
    for (int ks = 0; ks < 4; ++ks) {
        int kb2 = (ks * 32 + lg * 4) * 2;          // byte offset of k-half 0
        #pragma unroll
        for (int m = 0; m < 4; ++m) {
            int row  = wr * 64 + m * 16 + li;
            uint bse = (uint)(row << 8);
            uint swz = (uint)((row & 7) << 4);
            uint o0  = (bse + kb2) ^ swz;
            uint o1  = (bse + kb2 + 32) ^ swz;     // k-half 1 (+16 elems)
            ushort4 h0 = *(ushort4*)((char*)a_hi + o0);
            ushort4 h1 = *(ushort4*)((char*)a_hi + o1);
            ushort4 q0 = *(ushort4*)((char*)a_lo + o0);
            ushort4 q1 = *(ushort4*)((char*)a_lo + o1);
            bf16x8 ah = mkfrag(h0, h1);
            bf16x8 al = mkfrag(q0, q1);
            #pragma unroll
            for (int c = 0; c < 4; ++c) {
                acc[m][c] = __builtin_amdgcn_mfma_f32_16x16x32_bf16(ah, wfh[c][ks], acc[m][c], 0, 0, 0);
                acc[m][c] = __builtin_amdgcn_mfma_f32_16x16x32_bf16(ah, wfl[c][ks], acc[m][c], 0, 0, 0);
                acc[m][c] = __builtin_amdgcn_mfma_f32_16x16x32_bf16(al, wfh[c][ks], acc[m][c], 0, 0, 0);
            }
        }
    }

    // ---- epilogue: D frag row = lg*4 + i, col = li ----
    #pragma unroll
    for (int m = 0; m < 4; ++m) {
        #pragma unroll
        for (int i = 0; i < 4; ++i) {
            int n = n0 + wr * 64 + m * 16 + lg * 4 + i;
            if (n < N) {
                ushort* dst = hp + (size_t)n * 128 + wc * 64 + li;
                #pragma unroll
                for (int c = 0; c < 4; ++c)
                    dst[c * 16] = f2bf(acc[m][c][i]);
            }
        }
    }
}

// ---------------------------------------------------------------------------
// out[n] = bias + sum_{e in CSR[n]} p_e * hp[tgt_e]
// One wave per node, restructured for MLP: 4 edge slots x 16 lanes, each lane
// loads dwordx4 (16B) of the target row -> 4 edges per load instruction,
// 8 edges (2KB) in flight in the main loop. Partial sums per edge slot are
// combined with a stride-16/32 shfl_xor butterfly at node end.
// ---------------------------------------------------------------------------
__global__ __launch_bounds__(256) void agg_k(
    const int*  __restrict__ offs,
    const int2* __restrict__ ed,
    const ushort* __restrict__ hp,
    const float* __restrict__ bias,
    float*       __restrict__ out,
    int N)
{
    int wave = (blockIdx.x * blockDim.x + threadIdx.x) >> 6;
    int l    = threadIdx.x & 63;
    if (wave >= N) return;

    const int eg = l >> 4;        // edge slot 0..3
    const int cs = l & 15;        // column slice: cols cs*8..cs*8+7
    const int beg = offs[wave];
    const int end = offs[wave + 1];
    const uint4* hpq = (const uint4*)hp;   // 16 granules of 16B per row
    const float ps = 1.0f / 32768.0f;

    float acc[8];
    #pragma unroll
    for (int k = 0; k < 8; ++k) acc[k] = 0.f;

    int i = beg;
    for (; i + 8 <= end; i += 8) {
        int2 d0 = ed[i + eg];
        int2 d1 = ed[i + 4 + eg];
        uint4 q0 = hpq[(size_t)d0.x * 16 + cs];
        uint4 q1 = hpq[(size_t)d1.x * 16 + cs];
        float p0 = (float)(d0.y & 0x7fff) * ps;
        float p1 = (float)(d1.y & 0x7fff) * ps;
        uint u;
        u = q0.x; acc[0] += p0 * __uint_as_float(u << 16); acc[1] += p0 * __uint_as_float(u & 0xffff0000u);
        u = q0.y; acc[2] += p0 * __uint_as_float(u << 16); acc[3] += p0 * __uint_as_float(u & 0xffff0000u);
        u = q0.z; acc[4] += p0 * __uint_as_float(u << 16); acc[5] += p0 * __uint_as_float(u & 0xffff0000u);
        u = q0.w; acc[6] += p0 * __uint_as_float(u << 16); acc[7] += p0 * __uint_as_float(u & 0xffff0000u);
        u = q1.x; acc[0] += p1 * __uint_as_float(u << 16); acc[1] += p1 * __uint_as_float(u & 0xffff0000u);
        u = q1.y; acc[2] += p1 * __uint_as_float(u << 16); acc[3] += p1 * __uint_as_float(u & 0xffff0000u);
        u = q1.z; acc[4] += p1 * __uint_as_float(u << 16); acc[5] += p1 * __uint_as_float(u & 0xffff0000u);
        u = q1.w; acc[6] += p1 * __uint_as_float(u << 16); acc[7] += p1 * __uint_as_float(u & 0xffff0000u);
    }
    for (; i < end; i += 4) {
        int e = i + eg;
        bool act = e < end;
        int2 d = act ? ed[e] : make_int2(0, 0);   // inactive: row 0, p = 0
        uint4 q = hpq[(size_t)d.x * 16 + cs];
        float p = (float)(d.y & 0x7fff) * ps;
        uint u;
        u = q.x; acc[0] += p * __uint_as_float(u << 16); acc[1] += p * __uint_as_float(u & 0xffff0000u);
        u = q.y; acc[2] += p * __uint_as_float(u << 16); acc[3] += p * __uint_as_float(u & 0xffff0000u);
        u = q.z; acc[4] += p * __uint_as_float(u << 16); acc[5] += p * __uint_as_float(u & 0xffff0000u);
        u = q.w; acc[6] += p * __uint_as_float(u << 16); acc[7] += p * __uint_as_float(u & 0xffff0000u);
    }

    // combine the 4 edge-slot partials (lanes with same cs, stride 16)
    #pragma unroll
    for (int k = 0; k < 8; ++k) {
        float v = acc[k];
        v += __shfl_xor(v, 16);
        v += __shfl_xor(v, 32);
        acc[k] = v;
    }

    // add bias once, each lane writes float2 at col cs*8 + eg*2
    float2 bv = ((const float2*)bias)[cs * 4 + eg];
    float2 r;
    r.x = acc[eg * 2]     + bv.x;
    r.y = acc[eg * 2 + 1] + bv.y;
    ((float2*)(out + (size_t)wave * HIDDEN))[cs * 4 + eg] = r;
}

extern "C" void kernel_launch(void* const* d_in, const int* in_sizes, int n_in,
                              void* d_out, int out_size, void* d_ws, size_t ws_size,
                              hipStream_t stream)
{
    const float* prob   = (const float*)d_in[0];
    const float* hidden = (const float*)d_in[1];
    const int*   ei     = (const int*)  d_in[2];
    const float* W      = (const float*)d_in[3];
    const float* bias   = (const float*)d_in[4];
    float*       out    = (float*)d_out;

    const int E  = in_sizes[0];
    const int N  = in_sizes[1] / HIDDEN;
    const int B  = (N + 1023) / 1024;        // scan blocks
    const int NB = (N + NPB - 1) / NPB;      // buckets (782)

    // Workspace layout:
    char* w = (char*)d_ws;
    int* cnt  = (int*)w;                     // N
    int* offs = cnt + N;                     // N+1
    int* bsum = offs + N + 1;                // B
    int* boff = bsum + B;                    // B
    int* gcur = boff + B;                    // NB
    size_t ib = ((size_t)(2 * N + 1 + 2 * B + NB) * 4 + 15) & ~(size_t)15;
    int2*   ed = (int2*)(w + ib);            // E * 8B
    ushort* hp = (ushort*)(w + ib + (size_t)E * 8);   // N*128 bf16
    ushort* wh = hp + (size_t)N * 128;       // 128*128 bf16 (W head)
    ushort* wl = wh + 128 * 128;             // 128*128 bf16 (W residual)

    hipMemsetAsync(cnt, 0, (size_t)N * sizeof(int), stream);

    int eb = (E + 255) / 256;
    count_k<<<eb, 256, 0, stream>>>(ei, cnt, E);
    scan1_k<<<B, 1024, 0, stream>>>(cnt, offs, bsum, N);
    scan2_k<<<1, 1024, 0, stream>>>(bsum, boff, offs, B, N, E);
    scan3_k<<<B, 1024, 0, stream>>>(offs, gcur, boff, N);
    bin_k<<<(E + CHUNK - 1) / CHUNK, 256, 0, stream>>>(ei, prob, gcur, ed, E, NB);
    sort_k<<<NB, 256, 0, stream>>>(offs, ed, N);
    wprep_k<<<64, 256, 0, stream>>>(W, wh, wl);
    gemm_mfma_k<<<(N + 127) / 128, 256, 0, stream>>>(hidden, wh, wl, hp, N);
    agg_k<<<(N + 3) / 4, 256, 0, stream>>>(offs, ed, hp, bias, out, N);
}